// Round 11
// baseline (300.209 us; speedup 1.0000x reference)
//
#include <hip/hip_runtime.h>

#define K_C    500
#define KPAD   512
#define DIM    768
#define NROWS  65536
#define BM     128
#define BK     64
#define NKT    (DIM / BK)      // 12 K-tiles
#define THREADS 512
#define TAU    1.0f

#define BBUF_BYTES 65536       // one B buffer: 8 chunks x 512 centers x 16B

// ---- d_ws layout (bytes) ----
#define WS_CSQ  64
#define WS_LIST 4096
#define WS_CHI  270336

typedef __attribute__((ext_vector_type(8)))  short bf16x8;
typedef __attribute__((ext_vector_type(16))) float f32x16;
typedef __attribute__((ext_vector_type(4)))  float f32x4;

__device__ __forceinline__ ushort f2bf(float f) {
    unsigned x = __float_as_uint(f);
    unsigned r = (x + 0x7fffu + ((x >> 16) & 1u)) >> 16;   // RNE
    return (ushort)r;
}

__device__ __forceinline__ bf16x8 pack_frag(f32x4 a, f32x4 b) {
    bf16x8 r;
    r[0] = (short)f2bf(a.x); r[1] = (short)f2bf(a.y);
    r[2] = (short)f2bf(a.z); r[3] = (short)f2bf(a.w);
    r[4] = (short)f2bf(b.x); r[5] = (short)f2bf(b.y);
    r[6] = (short)f2bf(b.z); r[7] = (short)f2bf(b.w);
    return r;
}

#define GLOAD16(g, l)                                                        \
    __builtin_amdgcn_global_load_lds(                                        \
        (__attribute__((address_space(1))) void*)(g),                        \
        (__attribute__((address_space(3))) void*)(l), 16, 0, 0)

// ---------------------------------------------------------------------------
// Pre-kernel 1: centers fp32 -> bf16 (RNE), BK=64 chunk-major tile layout:
// unit u = kt*4096 + j*512 + r  (kt 0..11, j 0..7, r 0..511) holds
// c[r][kt*64 + j*8 .. +7]. Zero-pads rows 500..511; zeroes rescue counter.
// ---------------------------------------------------------------------------
__global__ void convert_kernel(const float* __restrict__ c, ushort* __restrict__ chi,
                               int* __restrict__ count) {
    int gid = blockIdx.x * 256 + threadIdx.x;
    if (gid == 0) *count = 0;
    int kt = gid >> 12;
    int j  = (gid >> 9) & 7;
    int r  = gid & 511;
    int kbase = kt * 64 + j * 8;

    ushort h[8];
    if (r < K_C) {
        #pragma unroll
        for (int e = 0; e < 8; ++e) h[e] = f2bf(c[(size_t)r * DIM + kbase + e]);
    } else {
        #pragma unroll
        for (int e = 0; e < 8; ++e) h[e] = 0;
    }
    ushort* ph = chi + (size_t)gid * 8;
    #pragma unroll
    for (int e = 0; e < 8; ++e) ph[e] = h[e];
}

// ---------------------------------------------------------------------------
// Pre-kernel 2: csq[k] = ||c_k||^2 fp32; pads 500..511 with +INF.
// ---------------------------------------------------------------------------
__global__ void csq_kernel(const float* __restrict__ c, float* __restrict__ csq) {
    int wid  = (blockIdx.x * blockDim.x + threadIdx.x) >> 6;
    int lane = threadIdx.x & 63;
    if (wid >= KPAD) return;
    if (wid >= K_C) { if (lane == 0) csq[wid] = INFINITY; return; }
    const float* row = c + (size_t)wid * DIM;
    float s = 0.f;
    #pragma unroll
    for (int j = 0; j < DIM / 64; ++j) {
        float v = row[lane + j * 64];
        s += v * v;
    }
    #pragma unroll
    for (int m = 32; m; m >>= 1) s += __shfl_xor(s, m, 64);
    if (lane == 0) csq[wid] = s;
}

// ---------------------------------------------------------------------------
// Main kernel (round 11): 128 rows x 512 centers, grid 512, 8 waves = 2m x 4n,
// Mf=2 x Nf=4, BK=64 -> 12 iters (24 sequential slots chip-wide, half of r10).
// NO A-LDS: each wave loads its A fragments straight from global (16 asm
// dwordx4/iter; wn-duplication absorbed by L1/L2) and converts in-reg.
// B: 2 x 64KB LDS buffers via global_load_lds issued 1 iter ahead.
// ONE barrier/iter; counted waits only:
//   (a) vmcnt(16) lgkmcnt(0) + s_barrier  -> B(kt) landed, A(kt+1) in flight
//   (b) issue B(kt+1) (buf freed by barrier)
//   (c) compute: 16 ds_read_b128 + 32 MFMA
//   (d) vmcnt(8) -> A(kt+1) landed (B(kt+1) stays in flight); convert
//   (e) issue A(kt+2)
// ---------------------------------------------------------------------------
__global__ __launch_bounds__(THREADS, 2) void kmeans_mfma(
        const float* __restrict__ x, const char* __restrict__ ws,
        int* __restrict__ out) {
    __shared__ __align__(16) ushort Bh[2][8][KPAD][8];   // 128 KB
    __shared__ float rv1[4][BM];                         // 2 KB
    __shared__ float rv2[4][BM];                         // 2 KB
    __shared__ int   ridx[4][BM];                        // 2 KB

    const int tid  = threadIdx.x;
    const int w    = tid >> 6;          // wave 0..7
    const int lane = tid & 63;
    const int l31  = lane & 31;
    const int lh   = lane >> 5;
    const int wm   = w >> 2;            // 0..1 row half (64 rows each)
    const int wn   = w & 3;             // 0..3 col quarter (128 cols each)
    const int rowBase = blockIdx.x * BM;

    const char* wsChi = ws + WS_CHI;
    const float* csq  = (const float*)(ws + WS_CSQ);
    int* count = (int*)ws;
    int* list  = (int*)(ws + WS_LIST);

    // A fragment source base (per lane): row = rowBase + wm*64 + mf*32 + l31,
    // col = kt*64 + (2s+lh)*8. Offsets s*64B (+16B pair) are asm literals.
    const float* xA0 = x + (size_t)(rowBase + wm * 64 + l31) * DIM + lh * 8;
    const float* xA1 = xA0 + (size_t)32 * DIM;

    f32x16 acc[2][4] = {};
    f32x4  aq[2][4][2];    // in-flight fp32 A (A(kt+1)); constant-indexed
    bf16x8 fr[2][4];       // converted A fragments for current tile

#define ISSUE_B(T)                                                            \
    {                                                                         \
        const char* sB_ = wsChi + (size_t)(T) * 65536 + w * 8192 + lane * 16; \
        char* dB_ = ((char*)Bh) + ((T) & 1) * BBUF_BYTES + w * 8192;          \
        GLOAD16(sB_ + 0 * 1024, dB_ + 0 * 1024);                              \
        GLOAD16(sB_ + 1 * 1024, dB_ + 1 * 1024);                              \
        GLOAD16(sB_ + 2 * 1024, dB_ + 2 * 1024);                              \
        GLOAD16(sB_ + 3 * 1024, dB_ + 3 * 1024);                              \
        GLOAD16(sB_ + 4 * 1024, dB_ + 4 * 1024);                              \
        GLOAD16(sB_ + 5 * 1024, dB_ + 5 * 1024);                              \
        GLOAD16(sB_ + 6 * 1024, dB_ + 6 * 1024);                              \
        GLOAD16(sB_ + 7 * 1024, dB_ + 7 * 1024);                              \
    }

#define ISSUE_A(T)                                                            \
    {                                                                         \
        const float* pa0_ = xA0 + (size_t)(T) * BK;                           \
        const float* pa1_ = xA1 + (size_t)(T) * BK;                           \
        asm volatile(                                                         \
            "global_load_dwordx4 %0, %8, off\n\t"                             \
            "global_load_dwordx4 %1, %8, off offset:16\n\t"                   \
            "global_load_dwordx4 %2, %8, off offset:64\n\t"                   \
            "global_load_dwordx4 %3, %8, off offset:80\n\t"                   \
            "global_load_dwordx4 %4, %8, off offset:128\n\t"                  \
            "global_load_dwordx4 %5, %8, off offset:144\n\t"                  \
            "global_load_dwordx4 %6, %8, off offset:192\n\t"                  \
            "global_load_dwordx4 %7, %8, off offset:208"                      \
            : "=&v"(aq[0][0][0]), "=&v"(aq[0][0][1]),                         \
              "=&v"(aq[0][1][0]), "=&v"(aq[0][1][1]),                         \
              "=&v"(aq[0][2][0]), "=&v"(aq[0][2][1]),                         \
              "=&v"(aq[0][3][0]), "=&v"(aq[0][3][1])                          \
            : "v"(pa0_) : "memory");                                          \
        asm volatile(                                                         \
            "global_load_dwordx4 %0, %8, off\n\t"                             \
            "global_load_dwordx4 %1, %8, off offset:16\n\t"                   \
            "global_load_dwordx4 %2, %8, off offset:64\n\t"                   \
            "global_load_dwordx4 %3, %8, off offset:80\n\t"                   \
            "global_load_dwordx4 %4, %8, off offset:128\n\t"                  \
            "global_load_dwordx4 %5, %8, off offset:144\n\t"                  \
            "global_load_dwordx4 %6, %8, off offset:192\n\t"                  \
            "global_load_dwordx4 %7, %8, off offset:208"                      \
            : "=&v"(aq[1][0][0]), "=&v"(aq[1][0][1]),                         \
              "=&v"(aq[1][1][0]), "=&v"(aq[1][1][1]),                         \
              "=&v"(aq[1][2][0]), "=&v"(aq[1][2][1]),                         \
              "=&v"(aq[1][3][0]), "=&v"(aq[1][3][1])                          \
            : "v"(pa1_) : "memory");                                          \
    }

#define CVT_A()                                                               \
    {                                                                         \
        _Pragma("unroll")                                                     \
        for (int mf_ = 0; mf_ < 2; ++mf_)                                     \
            _Pragma("unroll")                                                 \
            for (int s_ = 0; s_ < 4; ++s_)                                    \
                fr[mf_][s_] = pack_frag(aq[mf_][s_][0], aq[mf_][s_][1]);      \
    }

    // ---- prologue ----
    ISSUE_A(0);
    ISSUE_B(0);
    asm volatile("s_waitcnt vmcnt(8)" ::: "memory");   // A(0) landed
    __builtin_amdgcn_sched_barrier(0);
    CVT_A();
    ISSUE_A(1);

#define STEP(KT, DOB, DOA, DOCVT, VMA)                                        \
    {                                                                         \
        const int kt_ = (KT);                                                 \
        asm volatile("s_waitcnt vmcnt(" VMA ") lgkmcnt(0)\n\t"                \
                     "s_barrier" ::: "memory");                               \
        if (DOB) ISSUE_B(kt_ + 1);                                            \
        {                                                                     \
            const ushort* bbase_ =                                            \
                (const ushort*)(((const char*)Bh) + (kt_ & 1) * BBUF_BYTES);  \
            __builtin_amdgcn_s_setprio(1);                                    \
            _Pragma("unroll")                                                 \
            for (int s_ = 0; s_ < 4; ++s_) {                                  \
                const int j_ = s_ * 2 + lh;                                   \
                const ushort* pB_ = bbase_ + ((j_ * 512) + wn * 128 + l31) * 8;\
                _Pragma("unroll")                                             \
                for (int nf_ = 0; nf_ < 4; ++nf_) {                           \
                    bf16x8 bh_ = *(const bf16x8*)(pB_ + nf_ * 32 * 8);        \
                    acc[0][nf_] = __builtin_amdgcn_mfma_f32_32x32x16_bf16(    \
                        fr[0][s_], bh_, acc[0][nf_], 0, 0, 0);                \
                    acc[1][nf_] = __builtin_amdgcn_mfma_f32_32x32x16_bf16(    \
                        fr[1][s_], bh_, acc[1][nf_], 0, 0, 0);                \
                }                                                             \
            }                                                                 \
            __builtin_amdgcn_s_setprio(0);                                    \
        }                                                                     \
        if (DOCVT) {                                                          \
            asm volatile("s_waitcnt vmcnt(8)" ::: "memory");                  \
            __builtin_amdgcn_sched_barrier(0);                                \
            CVT_A();                                                          \
        }                                                                     \
        if (DOA) ISSUE_A(kt_ + 2);                                            \
    }

    for (int kt = 0; kt < NKT - 2; ++kt) STEP(kt, 1, 1, 1, "16");
    STEP(NKT - 2, 1, 0, 1, "16");
    STEP(NKT - 1, 0, 0, 0, "0");

#undef STEP
#undef ISSUE_A
#undef ISSUE_B
#undef CVT_A

    // ---- epilogue: per-row (best, second, idx) over this wave's 128 cols ----
    float cq[4];
    #pragma unroll
    for (int nf = 0; nf < 4; ++nf) cq[nf] = csq[wn * 128 + nf * 32 + l31];

    #pragma unroll
    for (int mf = 0; mf < 2; ++mf) {
        #pragma unroll
        for (int reg = 0; reg < 16; ++reg) {
            float v[4]; int col[4];
            #pragma unroll
            for (int nf = 0; nf < 4; ++nf) {
                v[nf]   = fmaf(-2.f, acc[mf][nf][reg], cq[nf]);
                col[nf] = wn * 128 + nf * 32 + l31;
            }
            float paL, paH; int paI;
            if (v[1] < v[0]) { paL = v[1]; paI = col[1]; paH = v[0]; }
            else             { paL = v[0]; paI = col[0]; paH = v[1]; }
            float pbL, pbH; int pbI;
            if (v[3] < v[2]) { pbL = v[3]; pbI = col[3]; pbH = v[2]; }
            else             { pbL = v[2]; pbI = col[2]; pbH = v[3]; }
            float b1, b2; int i1;
            if (pbL < paL) { b1 = pbL; i1 = pbI; b2 = fminf(paL, pbH); }
            else           { b1 = paL; i1 = paI; b2 = fminf(pbL, paH); }
            #pragma unroll
            for (int m = 1; m < 32; m <<= 1) {
                float o1 = __shfl_xor(b1, m, 64);
                float o2 = __shfl_xor(b2, m, 64);
                int   oi = __shfl_xor(i1, m, 64);
                b2 = fminf(fminf(b2, o2), fmaxf(b1, o1));
                if (o1 < b1 || (o1 == b1 && oi < i1)) { b1 = o1; i1 = oi; }
            }
            int row = wm * 64 + mf * 32 + (reg & 3) + 8 * (reg >> 2) + 4 * lh;
            if (l31 == 0) { rv1[wn][row] = b1; rv2[wn][row] = b2; ridx[wn][row] = i1; }
        }
    }
    __syncthreads();

    // ---- merge 4 col-quarters per row, write out, flag tight margins ----
    if (tid < BM) {
        float b1 = INFINITY, b2 = INFINITY; int i1 = 0;
        #pragma unroll
        for (int ww = 0; ww < 4; ++ww) {
            float a1 = rv1[ww][tid], a2 = rv2[ww][tid];
            int   ai = ridx[ww][tid];
            b2 = fminf(fminf(b2, a2), fmaxf(b1, a1));
            if (a1 < b1 || (a1 == b1 && ai < i1)) { b1 = a1; i1 = ai; }
        }
        out[rowBase + tid] = i1;
        if (b2 - b1 < TAU) {
            int p = atomicAdd(count, 1);
            list[p] = rowBase + tid;
        }
    }
}

// ---------------------------------------------------------------------------
// Rescue v4: exact fp32, register-tiled so LDS reads amortize (r8's v3 was
// LDS-read-bound: 16 reads / 128 FMA -> 62 us/block). 512 threads =
// 2 row-groups x 256 center-pairs; per thread 8 rows x 2 centers:
// per d4-step: 8 LDS b128 + 2 global b128 + 128 FMA. 16 rows/block.
// ---------------------------------------------------------------------------
__global__ __launch_bounds__(512) void rescue_kernel(
        const float* __restrict__ x, const float* __restrict__ c,
        const char* __restrict__ ws, int* __restrict__ out) {
    __shared__ __align__(16) float xs[16][DIM];   // 48 KB
    __shared__ float mv[16][4];
    __shared__ int   mi[16][4];
    __shared__ int   rows_s[16];
    const float* csq = (const float*)(ws + WS_CSQ);
    const int* list  = (const int*)(ws + WS_LIST);
    const int n = *(const int*)ws;
    const int tid  = threadIdx.x;
    const int wv   = tid >> 6;          // wave 0..7
    const int rg   = tid >> 8;          // row group 0..1 (rows rg*8..+7)
    const int cg   = tid & 255;         // center pair id
    const int k0 = cg;                  // centers k0, k0+256 (asc for ties)
    const int k1 = cg + 256;
    const float* c0 = c + (size_t)min(k0, K_C - 1) * DIM;
    const float* c1 = c + (size_t)min(k1, K_C - 1) * DIM;
    const float cq0 = csq[k0];
    const float cq1 = csq[k1];

    for (int g = blockIdx.x; g * 16 < n; g += gridDim.x) {
        const int base = g * 16;
        const int cnt  = min(16, n - base);
        if (tid < 16) rows_s[tid] = list[base + min(tid, cnt - 1)];
        __syncthreads();
        for (int idx = tid; idx < 16 * (DIM / 4); idx += 512) {
            int r = idx / (DIM / 4), dc = idx - r * (DIM / 4);
            *reinterpret_cast<float4*>(&xs[r][dc * 4]) =
                *reinterpret_cast<const float4*>(&x[(size_t)rows_s[r] * DIM + dc * 4]);
        }
        __syncthreads();

        float d0[8], d1[8];
        #pragma unroll
        for (int i = 0; i < 8; ++i) { d0[i] = 0.f; d1[i] = 0.f; }

        #pragma unroll 2
        for (int dq = 0; dq < DIM / 4; ++dq) {
            float4 cv0 = *reinterpret_cast<const float4*>(&c0[dq * 4]);
            float4 cv1 = *reinterpret_cast<const float4*>(&c1[dq * 4]);
            #pragma unroll
            for (int i = 0; i < 8; ++i) {
                float4 xv = *reinterpret_cast<const float4*>(&xs[rg * 8 + i][dq * 4]);
                d0[i] = fmaf(xv.x, cv0.x, d0[i]);
                d0[i] = fmaf(xv.y, cv0.y, d0[i]);
                d0[i] = fmaf(xv.z, cv0.z, d0[i]);
                d0[i] = fmaf(xv.w, cv0.w, d0[i]);
                d1[i] = fmaf(xv.x, cv1.x, d1[i]);
                d1[i] = fmaf(xv.y, cv1.y, d1[i]);
                d1[i] = fmaf(xv.z, cv1.z, d1[i]);
                d1[i] = fmaf(xv.w, cv1.w, d1[i]);
            }
        }

        float bv[8]; int bi[8];
        #pragma unroll
        for (int i = 0; i < 8; ++i) {
            float v0 = fmaf(-2.f, d0[i], cq0);
            float v1 = fmaf(-2.f, d1[i], cq1);
            if (v1 < v0) { bv[i] = v1; bi[i] = k1; }
            else         { bv[i] = v0; bi[i] = k0; }   // k0 < k1: ties keep k0
        }
        #pragma unroll
        for (int m = 1; m < 64; m <<= 1) {
            #pragma unroll
            for (int i = 0; i < 8; ++i) {
                float ov = __shfl_xor(bv[i], m, 64);
                int   oi = __shfl_xor(bi[i], m, 64);
                if (ov < bv[i] || (ov == bv[i] && oi < bi[i])) { bv[i] = ov; bi[i] = oi; }
            }
        }
        if ((tid & 63) == 0) {
            #pragma unroll
            for (int i = 0; i < 8; ++i) { mv[rg * 8 + i][wv & 3] = bv[i]; mi[rg * 8 + i][wv & 3] = bi[i]; }
        }
        __syncthreads();
        if (tid < cnt) {
            float b = mv[tid][0]; int i = mi[tid][0];
            #pragma unroll
            for (int q = 1; q < 4; ++q) {
                if (mv[tid][q] < b || (mv[tid][q] == b && mi[tid][q] < i)) {
                    b = mv[tid][q]; i = mi[tid][q];
                }
            }
            out[rows_s[tid]] = i;
        }
        __syncthreads();
    }
}

extern "C" void kernel_launch(void* const* d_in, const int* in_sizes, int n_in,
                              void* d_out, int out_size, void* d_ws, size_t ws_size,
                              hipStream_t stream) {
    const float* x = (const float*)d_in[0];
    const float* c = (const float*)d_in[1];
    char* ws = (char*)d_ws;
    int* out = (int*)d_out;

    convert_kernel<<<dim3(192), dim3(256), 0, stream>>>(
        c, (ushort*)(ws + WS_CHI), (int*)ws);
    csq_kernel<<<dim3(128), dim3(256), 0, stream>>>(c, (float*)(ws + WS_CSQ));
    kmeans_mfma<<<dim3(NROWS / BM), dim3(THREADS), 0, stream>>>(x, ws, out);
    rescue_kernel<<<dim3(256), dim3(512), 0, stream>>>(x, c, ws, out);
}

// Round 12
// 285.399 us; speedup vs baseline: 1.0519x; 1.0519x over previous
//
#include <hip/hip_runtime.h>

#define K_C    500
#define KPAD   512
#define DIM    768
#define NROWS  65536
#define BM     128
#define NKT    24              // K-tiles of 32
#define THREADS 512
#define TAU    1.0f

// ---- d_ws layout (bytes) ----
#define WS_CSQ  64
#define WS_LIST 4096
#define WS_CHI  270336

typedef __attribute__((ext_vector_type(8)))  short bf16x8;
typedef __attribute__((ext_vector_type(16))) float f32x16;
typedef __attribute__((ext_vector_type(4)))  float f32x4;

__device__ __forceinline__ ushort f2bf(float f) {
    unsigned x = __float_as_uint(f);
    unsigned r = (x + 0x7fffu + ((x >> 16) & 1u)) >> 16;   // RNE
    return (ushort)r;
}

__device__ __forceinline__ bf16x8 pack_frag(f32x4 a, f32x4 b) {
    bf16x8 r;
    r[0] = (short)f2bf(a.x); r[1] = (short)f2bf(a.y);
    r[2] = (short)f2bf(a.z); r[3] = (short)f2bf(a.w);
    r[4] = (short)f2bf(b.x); r[5] = (short)f2bf(b.y);
    r[6] = (short)f2bf(b.z); r[7] = (short)f2bf(b.w);
    return r;
}

// ---------------------------------------------------------------------------
// Pre-kernel 1: centers fp32 -> bf16 (RNE), chunk-major tile layout (BK=32):
// unit u = kt*2048 + j*512 + r (kt 0..23, j 0..3, r 0..511) holds
// c[r][kt*32 + j*8 .. +7]. Zero-pads rows 500..511; zeroes rescue counter.
// ---------------------------------------------------------------------------
__global__ void convert_kernel(const float* __restrict__ c, ushort* __restrict__ chi,
                               int* __restrict__ count) {
    int gid = blockIdx.x * 256 + threadIdx.x;
    if (gid == 0) *count = 0;
    int kt = gid >> 11;
    int u  = gid & 2047;
    int j  = u >> 9;
    int r  = u & 511;
    int kbase = kt * 32 + j * 8;

    ushort h[8];
    if (r < K_C) {
        #pragma unroll
        for (int e = 0; e < 8; ++e) h[e] = f2bf(c[(size_t)r * DIM + kbase + e]);
    } else {
        #pragma unroll
        for (int e = 0; e < 8; ++e) h[e] = 0;
    }
    ushort* ph = chi + (size_t)gid * 8;
    #pragma unroll
    for (int e = 0; e < 8; ++e) ph[e] = h[e];
}

// ---------------------------------------------------------------------------
// Pre-kernel 2: csq[k] = ||c_k||^2 fp32; pads 500..511 with +INF.
// ---------------------------------------------------------------------------
__global__ void csq_kernel(const float* __restrict__ c, float* __restrict__ csq) {
    int wid  = (blockIdx.x * blockDim.x + threadIdx.x) >> 6;
    int lane = threadIdx.x & 63;
    if (wid >= KPAD) return;
    if (wid >= K_C) { if (lane == 0) csq[wid] = INFINITY; return; }
    const float* row = c + (size_t)wid * DIM;
    float s = 0.f;
    #pragma unroll
    for (int j = 0; j < DIM / 64; ++j) {
        float v = row[lane + j * 64];
        s += v * v;
    }
    #pragma unroll
    for (int m = 32; m; m >>= 1) s += __shfl_xor(s, m, 64);
    if (lane == 0) csq[wid] = s;
}

// ---------------------------------------------------------------------------
// Main kernel (round 12): BARRIER-FREE, LDS-FREE operand path.
// 128 rows x 512 centers per block, grid 512, 8 waves = 2m x 4n, Mf2 x Nf4.
// B fragments load DIRECTLY global->reg from the chunk-major ws tiles
// (coalesced: 32 consecutive 16B units per half-wave). A fragments load
// per-lane from x (row gather; each 128B x-line fully consumed within one
// iteration by 2 lanes x 4 wn-waves -> L1 absorbs duplication) and convert
// in-reg. NO s_barrier in the K-loop -> every wave free-runs; the compiler
// software-pipelines the loads (nothing blocks code motion).
// LDS: 6 KB epilogue scratch only.
// ---------------------------------------------------------------------------
__global__ __launch_bounds__(THREADS, 2) void kmeans_mfma(
        const float* __restrict__ x, const char* __restrict__ ws,
        int* __restrict__ out) {
    __shared__ float rv1[4][BM];                         // 2 KB
    __shared__ float rv2[4][BM];                         // 2 KB
    __shared__ int   ridx[4][BM];                        // 2 KB

    const int tid  = threadIdx.x;
    const int w    = tid >> 6;          // wave 0..7
    const int lane = tid & 63;
    const int l31  = lane & 31;
    const int lh   = lane >> 5;
    const int wm   = w >> 2;            // 0..1 row half (64 rows each)
    const int wn   = w & 3;             // 0..3 col quarter (128 cols each)
    const int rowBase = blockIdx.x * BM;

    const ushort* __restrict__ Bws = (const ushort*)(ws + WS_CHI);
    const float* csq  = (const float*)(ws + WS_CSQ);
    int* count = (int*)ws;
    int* list  = (int*)(ws + WS_LIST);

    // A source: lane covers row rowBase + wm*64 + mf*32 + l31, k-chunk j=ks*2+lh
    const float* __restrict__ pA0 =
        x + (size_t)(rowBase + wm * 64 + l31) * DIM + lh * 8;
    const float* __restrict__ pA1 = pA0 + (size_t)32 * DIM;
    // B source: unit (kt*4 + ks*2 + lh)*512 + wn*128 + nf*32 + l31, x8 ushorts
    const ushort* __restrict__ pB0 = Bws + ((size_t)lh * 512 + wn * 128 + l31) * 8;

    f32x16 acc[2][4] = {};

    #pragma unroll 2
    for (int kt = 0; kt < NKT; ++kt) {
        const float* a0 = pA0 + kt * 32;
        const float* a1 = pA1 + kt * 32;
        const ushort* bb = pB0 + (size_t)kt * 16384;   // kt*4*512*8 ushorts

        bf16x8 f0[2], f1[2];
        #pragma unroll
        for (int ks = 0; ks < 2; ++ks) {
            f32x4 p00 = *reinterpret_cast<const f32x4*>(a0 + ks * 16);
            f32x4 p01 = *reinterpret_cast<const f32x4*>(a0 + ks * 16 + 4);
            f32x4 p10 = *reinterpret_cast<const f32x4*>(a1 + ks * 16);
            f32x4 p11 = *reinterpret_cast<const f32x4*>(a1 + ks * 16 + 4);
            f0[ks] = pack_frag(p00, p01);
            f1[ks] = pack_frag(p10, p11);
        }

        #pragma unroll
        for (int ks = 0; ks < 2; ++ks) {
            const ushort* pB = bb + ks * 8192;         // ks*2*512*8 ushorts
            #pragma unroll
            for (int nf = 0; nf < 4; ++nf) {
                bf16x8 bh = *reinterpret_cast<const bf16x8*>(pB + nf * 256);
                acc[0][nf] = __builtin_amdgcn_mfma_f32_32x32x16_bf16(
                    f0[ks], bh, acc[0][nf], 0, 0, 0);
                acc[1][nf] = __builtin_amdgcn_mfma_f32_32x32x16_bf16(
                    f1[ks], bh, acc[1][nf], 0, 0, 0);
            }
        }
    }

    // ---- epilogue: per-row (best, second, idx) over this wave's 128 cols ----
    float cq[4];
    #pragma unroll
    for (int nf = 0; nf < 4; ++nf) cq[nf] = csq[wn * 128 + nf * 32 + l31];

    #pragma unroll
    for (int mf = 0; mf < 2; ++mf) {
        #pragma unroll
        for (int reg = 0; reg < 16; ++reg) {
            float v[4]; int col[4];
            #pragma unroll
            for (int nf = 0; nf < 4; ++nf) {
                v[nf]   = fmaf(-2.f, acc[mf][nf][reg], cq[nf]);
                col[nf] = wn * 128 + nf * 32 + l31;
            }
            float paL, paH; int paI;
            if (v[1] < v[0]) { paL = v[1]; paI = col[1]; paH = v[0]; }
            else             { paL = v[0]; paI = col[0]; paH = v[1]; }
            float pbL, pbH; int pbI;
            if (v[3] < v[2]) { pbL = v[3]; pbI = col[3]; pbH = v[2]; }
            else             { pbL = v[2]; pbI = col[2]; pbH = v[3]; }
            float b1, b2; int i1;
            if (pbL < paL) { b1 = pbL; i1 = pbI; b2 = fminf(paL, pbH); }
            else           { b1 = paL; i1 = paI; b2 = fminf(pbL, paH); }
            #pragma unroll
            for (int m = 1; m < 32; m <<= 1) {
                float o1 = __shfl_xor(b1, m, 64);
                float o2 = __shfl_xor(b2, m, 64);
                int   oi = __shfl_xor(i1, m, 64);
                b2 = fminf(fminf(b2, o2), fmaxf(b1, o1));
                if (o1 < b1 || (o1 == b1 && oi < i1)) { b1 = o1; i1 = oi; }
            }
            int row = wm * 64 + mf * 32 + (reg & 3) + 8 * (reg >> 2) + 4 * lh;
            if (l31 == 0) { rv1[wn][row] = b1; rv2[wn][row] = b2; ridx[wn][row] = i1; }
        }
    }
    __syncthreads();

    // ---- merge 4 col-quarters per row, write out, flag tight margins ----
    if (tid < BM) {
        float b1 = INFINITY, b2 = INFINITY; int i1 = 0;
        #pragma unroll
        for (int ww = 0; ww < 4; ++ww) {
            float a1 = rv1[ww][tid], a2 = rv2[ww][tid];
            int   ai = ridx[ww][tid];
            b2 = fminf(fminf(b2, a2), fmaxf(b1, a1));
            if (a1 < b1 || (a1 == b1 && ai < i1)) { b1 = a1; i1 = ai; }
        }
        out[rowBase + tid] = i1;
        if (b2 - b1 < TAU) {
            int p = atomicAdd(count, 1);
            list[p] = rowBase + tid;
        }
    }
}

// ---------------------------------------------------------------------------
// Rescue v4 (unchanged): exact fp32, register-tiled. 512 threads =
// 2 row-groups x 256 center-pairs; per thread 8 rows x 2 centers.
// ---------------------------------------------------------------------------
__global__ __launch_bounds__(512) void rescue_kernel(
        const float* __restrict__ x, const float* __restrict__ c,
        const char* __restrict__ ws, int* __restrict__ out) {
    __shared__ __align__(16) float xs[16][DIM];   // 48 KB
    __shared__ float mv[16][4];
    __shared__ int   mi[16][4];
    __shared__ int   rows_s[16];
    const float* csq = (const float*)(ws + WS_CSQ);
    const int* list  = (const int*)(ws + WS_LIST);
    const int n = *(const int*)ws;
    const int tid  = threadIdx.x;
    const int wv   = tid >> 6;          // wave 0..7
    const int rg   = tid >> 8;          // row group 0..1 (rows rg*8..+7)
    const int cg   = tid & 255;         // center pair id
    const int k0 = cg;                  // centers k0, k0+256 (asc for ties)
    const int k1 = cg + 256;
    const float* c0 = c + (size_t)min(k0, K_C - 1) * DIM;
    const float* c1 = c + (size_t)min(k1, K_C - 1) * DIM;
    const float cq0 = csq[k0];
    const float cq1 = csq[k1];

    for (int g = blockIdx.x; g * 16 < n; g += gridDim.x) {
        const int base = g * 16;
        const int cnt  = min(16, n - base);
        if (tid < 16) rows_s[tid] = list[base + min(tid, cnt - 1)];
        __syncthreads();
        for (int idx = tid; idx < 16 * (DIM / 4); idx += 512) {
            int r = idx / (DIM / 4), dc = idx - r * (DIM / 4);
            *reinterpret_cast<float4*>(&xs[r][dc * 4]) =
                *reinterpret_cast<const float4*>(&x[(size_t)rows_s[r] * DIM + dc * 4]);
        }
        __syncthreads();

        float d0[8], d1[8];
        #pragma unroll
        for (int i = 0; i < 8; ++i) { d0[i] = 0.f; d1[i] = 0.f; }

        #pragma unroll 2
        for (int dq = 0; dq < DIM / 4; ++dq) {
            float4 cv0 = *reinterpret_cast<const float4*>(&c0[dq * 4]);
            float4 cv1 = *reinterpret_cast<const float4*>(&c1[dq * 4]);
            #pragma unroll
            for (int i = 0; i < 8; ++i) {
                float4 xv = *reinterpret_cast<const float4*>(&xs[rg * 8 + i][dq * 4]);
                d0[i] = fmaf(xv.x, cv0.x, d0[i]);
                d0[i] = fmaf(xv.y, cv0.y, d0[i]);
                d0[i] = fmaf(xv.z, cv0.z, d0[i]);
                d0[i] = fmaf(xv.w, cv0.w, d0[i]);
                d1[i] = fmaf(xv.x, cv1.x, d1[i]);
                d1[i] = fmaf(xv.y, cv1.y, d1[i]);
                d1[i] = fmaf(xv.z, cv1.z, d1[i]);
                d1[i] = fmaf(xv.w, cv1.w, d1[i]);
            }
        }

        float bv[8]; int bi[8];
        #pragma unroll
        for (int i = 0; i < 8; ++i) {
            float v0 = fmaf(-2.f, d0[i], cq0);
            float v1 = fmaf(-2.f, d1[i], cq1);
            if (v1 < v0) { bv[i] = v1; bi[i] = k1; }
            else         { bv[i] = v0; bi[i] = k0; }   // k0 < k1: ties keep k0
        }
        #pragma unroll
        for (int m = 1; m < 64; m <<= 1) {
            #pragma unroll
            for (int i = 0; i < 8; ++i) {
                float ov = __shfl_xor(bv[i], m, 64);
                int   oi = __shfl_xor(bi[i], m, 64);
                if (ov < bv[i] || (ov == bv[i] && oi < bi[i])) { bv[i] = ov; bi[i] = oi; }
            }
        }
        if ((tid & 63) == 0) {
            #pragma unroll
            for (int i = 0; i < 8; ++i) { mv[rg * 8 + i][wv & 3] = bv[i]; mi[rg * 8 + i][wv & 3] = bi[i]; }
        }
        __syncthreads();
        if (tid < cnt) {
            float b = mv[tid][0]; int i = mi[tid][0];
            #pragma unroll
            for (int q = 1; q < 4; ++q) {
                if (mv[tid][q] < b || (mv[tid][q] == b && mi[tid][q] < i)) {
                    b = mv[tid][q]; i = mi[tid][q];
                }
            }
            out[rows_s[tid]] = i;
        }
        __syncthreads();
    }
}

extern "C" void kernel_launch(void* const* d_in, const int* in_sizes, int n_in,
                              void* d_out, int out_size, void* d_ws, size_t ws_size,
                              hipStream_t stream) {
    const float* x = (const float*)d_in[0];
    const float* c = (const float*)d_in[1];
    char* ws = (char*)d_ws;
    int* out = (int*)d_out;

    convert_kernel<<<dim3(192), dim3(256), 0, stream>>>(
        c, (ushort*)(ws + WS_CHI), (int*)ws);
    csq_kernel<<<dim3(128), dim3(256), 0, stream>>>(c, (float*)(ws + WS_CSQ));
    kmeans_mfma<<<dim3(NROWS / BM), dim3(THREADS), 0, stream>>>(x, ws, out);
    rescue_kernel<<<dim3(256), dim3(512), 0, stream>>>(x, c, ws, out);
}

// Round 13
// 209.267 us; speedup vs baseline: 1.4346x; 1.3638x over previous
//
#include <hip/hip_runtime.h>

#define K_C    500
#define KPAD   512
#define DIM    768
#define NROWS  65536
#define BM     64
#define BK     32
#define NKT    (DIM / BK)      // 24 K-tiles
#define THREADS 512
#define TAU    1.0f

// ---- d_ws layout (bytes) ----
#define WS_CSQ  64
#define WS_LIST 4096
#define WS_CHI  270336

typedef __attribute__((ext_vector_type(8)))  short bf16x8;
typedef __attribute__((ext_vector_type(16))) float f32x16;

__device__ __forceinline__ ushort f2bf(float f) {
    unsigned x = __float_as_uint(f);
    unsigned r = (x + 0x7fffu + ((x >> 16) & 1u)) >> 16;   // RNE
    return (ushort)r;
}

#define GLOAD16(g, l)                                                        \
    __builtin_amdgcn_global_load_lds(                                        \
        (__attribute__((address_space(1))) void*)(g),                        \
        (__attribute__((address_space(3))) void*)(l), 16, 0, 0)

// ---------------------------------------------------------------------------
// Pre-kernel 1: centers fp32 -> bf16 (RNE), chunk-major tile layout:
// unit u = kt*2048 + j*512 + r holds c[r][kt*32 + j*8 .. +7]. Zero-pads
// rows 500..511 and zeroes the rescue counter.
// ---------------------------------------------------------------------------
__global__ void convert_kernel(const float* __restrict__ c, ushort* __restrict__ chi,
                               int* __restrict__ count) {
    int gid = blockIdx.x * 256 + threadIdx.x;
    if (gid == 0) *count = 0;
    int kt = gid >> 11;
    int u  = gid & 2047;
    int j  = u >> 9;
    int r  = u & 511;
    int kbase = kt * 32 + j * 8;

    ushort h[8];
    if (r < K_C) {
        #pragma unroll
        for (int e = 0; e < 8; ++e) h[e] = f2bf(c[(size_t)r * DIM + kbase + e]);
    } else {
        #pragma unroll
        for (int e = 0; e < 8; ++e) h[e] = 0;
    }
    ushort* ph = chi + (size_t)gid * 8;
    #pragma unroll
    for (int e = 0; e < 8; ++e) ph[e] = h[e];
}

// ---------------------------------------------------------------------------
// Pre-kernel 2: csq[k] = ||c_k||^2 fp32; pads 500..511 with +INF.
// ---------------------------------------------------------------------------
__global__ void csq_kernel(const float* __restrict__ c, float* __restrict__ csq) {
    int wid  = (blockIdx.x * blockDim.x + threadIdx.x) >> 6;
    int lane = threadIdx.x & 63;
    if (wid >= KPAD) return;
    if (wid >= K_C) { if (lane == 0) csq[wid] = INFINITY; return; }
    const float* row = c + (size_t)wid * DIM;
    float s = 0.f;
    #pragma unroll
    for (int j = 0; j < DIM / 64; ++j) {
        float v = row[lane + j * 64];
        s += v * v;
    }
    #pragma unroll
    for (int m = 32; m; m >>= 1) s += __shfl_xor(s, m, 64);
    if (lane == 0) csq[wid] = s;
}

// ---------------------------------------------------------------------------
// Main kernel (round 13): r8's verified structure, FIXED FOR CO-RESIDENCY.
// 64 rows x 512 centers, grid 1024, 8 waves = 2m x 4n, acc 64 AGPR + ~60
// VGPR = 124 unified regs -> 4 waves/SIMD; LDS ~40 KB (single 32 KB B
// buffer, no dbuf) -> TWO blocks per CU. r7/r8 silently ran 1 block/CU
// because LDS was 80.9 KB > 80; every round since ran 2 waves/SIMD and was
// latency-bound (MfmaUtil ~10%). The co-resident block now hides the
// stage-drain; plain __syncthreads(), no manual vmcnt.
// ---------------------------------------------------------------------------
__global__ __launch_bounds__(THREADS, 4) void kmeans_mfma(
        const float* __restrict__ x, const char* __restrict__ ws,
        int* __restrict__ out) {
    __shared__ __align__(16) ushort Bh[4][KPAD][8];      // 32 KB
    __shared__ __align__(16) ushort Ah[4][BM][8];        // 4 KB
    __shared__ float rv1[4][BM];                         // 1 KB
    __shared__ float rv2[4][BM];                         // 1 KB
    __shared__ int   ridx[4][BM];                        // 1 KB

    const int tid  = threadIdx.x;
    const int w    = tid >> 6;          // wave 0..7
    const int lane = tid & 63;
    const int l31  = lane & 31;
    const int lh   = lane >> 5;
    const int wm   = w >> 2;            // 0..1 row half (32 rows each)
    const int wn   = w & 3;             // 0..3 col quarter (128 cols each)
    const int rowBase = blockIdx.x * BM;

    // A staging (threads 0..255): thread t -> row t>>2 (0..63), k-chunk j = t&3
    const int srow = tid >> 2;
    const int sj   = tid & 3;
    const int sslot = srow ^ (sj << 1);   // bank-conflict-free write slot
    const bool stager = (tid < 256);
    const float* xsrc = x + (size_t)(rowBase + srow) * DIM + sj * 8;

    const char* wsChi = ws + WS_CHI;
    const float* csq  = (const float*)(ws + WS_CSQ);
    int* count = (int*)ws;
    int* list  = (int*)(ws + WS_LIST);

    f32x16 acc[4] = {};

    // ---- preload + convert A tile 0 ----
    uint4 hv;
    if (stager) {
        float4 xa = *reinterpret_cast<const float4*>(xsrc);
        float4 xb = *reinterpret_cast<const float4*>(xsrc + 4);
        float v[8] = {xa.x, xa.y, xa.z, xa.w, xb.x, xb.y, xb.z, xb.w};
        uint h[8];
        #pragma unroll
        for (int e = 0; e < 8; ++e) h[e] = f2bf(v[e]);
        hv = make_uint4(h[0] | (h[1] << 16), h[2] | (h[3] << 16),
                        h[4] | (h[5] << 16), h[6] | (h[7] << 16));
    }

    for (int kt = 0; kt < NKT; ++kt) {
        __syncthreads();   // (a) prev compute done; Bh/Ah safe to overwrite

        // ---- stage B(kt) via global_load_lds (single buffer) ----
        {
            const char* sH = wsChi + (size_t)kt * 32768 + w * 4096 + lane * 16;
            char* dH = ((char*)Bh) + w * 4096;
            #pragma unroll
            for (int i = 0; i < 4; ++i) GLOAD16(sH + i * 1024, dH + i * 1024);
        }
        // ---- A write (pre-converted regs -> LDS, swizzled slot) ----
        if (stager)
            *reinterpret_cast<uint4*>(&Ah[sj][sslot][0]) = hv;

        __syncthreads();   // (b) compiler drains vmcnt+lgkm: staged data visible

        // ---- prefetch next A floats (hidden under compute) ----
        float4 xa, xb;
        if (kt + 1 < NKT && stager) {
            xa = *reinterpret_cast<const float4*>(xsrc + (kt + 1) * BK);
            xb = *reinterpret_cast<const float4*>(xsrc + (kt + 1) * BK + 4);
        }

        // ---- compute: 2 k-steps of 16, 4 MFMAs each ----
        __builtin_amdgcn_s_setprio(1);
        #pragma unroll
        for (int ks = 0; ks < 2; ++ks) {
            const int j = ks * 2 + lh;
            const int rsl = (wm * 32 + l31) ^ (j << 1);   // read slot (swizzle inverse)
            bf16x8 ah0 = *(const bf16x8*)&Ah[j][rsl][0];

            const ushort* pBh = &Bh[j][wn * 128 + l31][0];
            #pragma unroll
            for (int nf = 0; nf < 4; ++nf) {
                bf16x8 bh = *(const bf16x8*)(pBh + nf * 32 * 8);
                acc[nf] = __builtin_amdgcn_mfma_f32_32x32x16_bf16(ah0, bh, acc[nf], 0, 0, 0);
            }
        }
        __builtin_amdgcn_s_setprio(0);

        // ---- convert next A tile ----
        if (kt + 1 < NKT && stager) {
            float v[8] = {xa.x, xa.y, xa.z, xa.w, xb.x, xb.y, xb.z, xb.w};
            uint h[8];
            #pragma unroll
            for (int e = 0; e < 8; ++e) h[e] = f2bf(v[e]);
            hv = make_uint4(h[0] | (h[1] << 16), h[2] | (h[3] << 16),
                            h[4] | (h[5] << 16), h[6] | (h[7] << 16));
        }
    }

    // ---- epilogue: per-row (best, second, idx) over this wave's 128 cols ----
    float cq[4];
    #pragma unroll
    for (int nf = 0; nf < 4; ++nf) cq[nf] = csq[wn * 128 + nf * 32 + l31];

    #pragma unroll
    for (int reg = 0; reg < 16; ++reg) {
        float v[4]; int col[4];
        #pragma unroll
        for (int nf = 0; nf < 4; ++nf) {
            v[nf]   = fmaf(-2.f, acc[nf][reg], cq[nf]);
            col[nf] = wn * 128 + nf * 32 + l31;
        }
        float paL, paH; int paI;
        if (v[1] < v[0]) { paL = v[1]; paI = col[1]; paH = v[0]; }
        else             { paL = v[0]; paI = col[0]; paH = v[1]; }
        float pbL, pbH; int pbI;
        if (v[3] < v[2]) { pbL = v[3]; pbI = col[3]; pbH = v[2]; }
        else             { pbL = v[2]; pbI = col[2]; pbH = v[3]; }
        float b1, b2; int i1;
        if (pbL < paL) { b1 = pbL; i1 = pbI; b2 = fminf(paL, pbH); }
        else           { b1 = paL; i1 = paI; b2 = fminf(pbL, paH); }
        #pragma unroll
        for (int m = 1; m < 32; m <<= 1) {
            float o1 = __shfl_xor(b1, m, 64);
            float o2 = __shfl_xor(b2, m, 64);
            int   oi = __shfl_xor(i1, m, 64);
            b2 = fminf(fminf(b2, o2), fmaxf(b1, o1));
            if (o1 < b1 || (o1 == b1 && oi < i1)) { b1 = o1; i1 = oi; }
        }
        int row = wm * 32 + (reg & 3) + 8 * (reg >> 2) + 4 * lh;
        if (l31 == 0) { rv1[wn][row] = b1; rv2[wn][row] = b2; ridx[wn][row] = i1; }
    }
    __syncthreads();

    // ---- merge 4 col-quarters per row, write out, flag tight margins ----
    if (tid < BM) {
        float b1 = INFINITY, b2 = INFINITY; int i1 = 0;
        #pragma unroll
        for (int ww = 0; ww < 4; ++ww) {
            float a1 = rv1[ww][tid], a2 = rv2[ww][tid];
            int   ai = ridx[ww][tid];
            b2 = fminf(fminf(b2, a2), fmaxf(b1, a1));
            if (a1 < b1 || (a1 == b1 && ai < i1)) { b1 = a1; i1 = ai; }
        }
        out[rowBase + tid] = i1;
        if (b2 - b1 < TAU) {
            int p = atomicAdd(count, 1);
            list[p] = rowBase + tid;
        }
    }
}

// ---------------------------------------------------------------------------
// Rescue v4 (unchanged from r12): exact fp32, register-tiled. 512 threads =
// 2 row-groups x 256 center-pairs; per thread 8 rows x 2 centers; LDS x
// reads are wave-uniform broadcasts.
// ---------------------------------------------------------------------------
__global__ __launch_bounds__(512) void rescue_kernel(
        const float* __restrict__ x, const float* __restrict__ c,
        const char* __restrict__ ws, int* __restrict__ out) {
    __shared__ __align__(16) float xs[16][DIM];   // 48 KB
    __shared__ float mv[16][4];
    __shared__ int   mi[16][4];
    __shared__ int   rows_s[16];
    const float* csq = (const float*)(ws + WS_CSQ);
    const int* list  = (const int*)(ws + WS_LIST);
    const int n = *(const int*)ws;
    const int tid  = threadIdx.x;
    const int wv   = tid >> 6;          // wave 0..7
    const int rg   = tid >> 8;          // row group 0..1 (rows rg*8..+7)
    const int cg   = tid & 255;         // center pair id
    const int k0 = cg;                  // centers k0, k0+256 (asc for ties)
    const int k1 = cg + 256;
    const float* c0 = c + (size_t)min(k0, K_C - 1) * DIM;
    const float* c1 = c + (size_t)min(k1, K_C - 1) * DIM;
    const float cq0 = csq[k0];
    const float cq1 = csq[k1];

    for (int g = blockIdx.x; g * 16 < n; g += gridDim.x) {
        const int base = g * 16;
        const int cnt  = min(16, n - base);
        if (tid < 16) rows_s[tid] = list[base + min(tid, cnt - 1)];
        __syncthreads();
        for (int idx = tid; idx < 16 * (DIM / 4); idx += 512) {
            int r = idx / (DIM / 4), dc = idx - r * (DIM / 4);
            *reinterpret_cast<float4*>(&xs[r][dc * 4]) =
                *reinterpret_cast<const float4*>(&x[(size_t)rows_s[r] * DIM + dc * 4]);
        }
        __syncthreads();

        float d0[8], d1[8];
        #pragma unroll
        for (int i = 0; i < 8; ++i) { d0[i] = 0.f; d1[i] = 0.f; }

        #pragma unroll 2
        for (int dq = 0; dq < DIM / 4; ++dq) {
            float4 cv0 = *reinterpret_cast<const float4*>(&c0[dq * 4]);
            float4 cv1 = *reinterpret_cast<const float4*>(&c1[dq * 4]);
            #pragma unroll
            for (int i = 0; i < 8; ++i) {
                float4 xv = *reinterpret_cast<const float4*>(&xs[rg * 8 + i][dq * 4]);
                d0[i] = fmaf(xv.x, cv0.x, d0[i]);
                d0[i] = fmaf(xv.y, cv0.y, d0[i]);
                d0[i] = fmaf(xv.z, cv0.z, d0[i]);
                d0[i] = fmaf(xv.w, cv0.w, d0[i]);
                d1[i] = fmaf(xv.x, cv1.x, d1[i]);
                d1[i] = fmaf(xv.y, cv1.y, d1[i]);
                d1[i] = fmaf(xv.z, cv1.z, d1[i]);
                d1[i] = fmaf(xv.w, cv1.w, d1[i]);
            }
        }

        float bv[8]; int bi[8];
        #pragma unroll
        for (int i = 0; i < 8; ++i) {
            float v0 = fmaf(-2.f, d0[i], cq0);
            float v1 = fmaf(-2.f, d1[i], cq1);
            if (v1 < v0) { bv[i] = v1; bi[i] = k1; }
            else         { bv[i] = v0; bi[i] = k0; }   // k0 < k1: ties keep k0
        }
        #pragma unroll
        for (int m = 1; m < 64; m <<= 1) {
            #pragma unroll
            for (int i = 0; i < 8; ++i) {
                float ov = __shfl_xor(bv[i], m, 64);
                int   oi = __shfl_xor(bi[i], m, 64);
                if (ov < bv[i] || (ov == bv[i] && oi < bi[i])) { bv[i] = ov; bi[i] = oi; }
            }
        }
        if ((tid & 63) == 0) {
            #pragma unroll
            for (int i = 0; i < 8; ++i) { mv[rg * 8 + i][wv & 3] = bv[i]; mi[rg * 8 + i][wv & 3] = bi[i]; }
        }
        __syncthreads();
        if (tid < cnt) {
            float b = mv[tid][0]; int i = mi[tid][0];
            #pragma unroll
            for (int q = 1; q < 4; ++q) {
                if (mv[tid][q] < b || (mv[tid][q] == b && mi[tid][q] < i)) {
                    b = mv[tid][q]; i = mi[tid][q];
                }
            }
            out[rows_s[tid]] = i;
        }
        __syncthreads();
    }
}

extern "C" void kernel_launch(void* const* d_in, const int* in_sizes, int n_in,
                              void* d_out, int out_size, void* d_ws, size_t ws_size,
                              hipStream_t stream) {
    const float* x = (const float*)d_in[0];
    const float* c = (const float*)d_in[1];
    char* ws = (char*)d_ws;
    int* out = (int*)d_out;

    convert_kernel<<<dim3(192), dim3(256), 0, stream>>>(
        c, (ushort*)(ws + WS_CHI), (int*)ws);
    csq_kernel<<<dim3(128), dim3(256), 0, stream>>>(c, (float*)(ws + WS_CSQ));
    kmeans_mfma<<<dim3(NROWS / BM), dim3(THREADS), 0, stream>>>(x, ws, out);
    rescue_kernel<<<dim3(256), dim3(512), 0, stream>>>(x, c, ws, out);
}